// Round 14
// baseline (313.848 us; speedup 1.0000x reference)
//
#include <hip/hip_runtime.h>
#include <stdint.h>

#define TS 2048
#define DM 2048
#define NH 16
#define DH 128

typedef unsigned short u16t;
typedef __attribute__((ext_vector_type(8))) short short8;
typedef __attribute__((ext_vector_type(4))) float f32x4;
typedef __attribute__((ext_vector_type(4))) unsigned int u32x4;
typedef __attribute__((ext_vector_type(4))) int i32x4;

__device__ __forceinline__ float bf2f(u16t b) {
  return __uint_as_float(((unsigned int)b) << 16);
}
__device__ __forceinline__ u16t f2bf(float f) {
  unsigned int u = __float_as_uint(f);
  u += 0x7FFFu + ((u >> 16) & 1u);   // round-to-nearest-even
  return (u16t)(u >> 16);
}

// async global->LDS, 16B per lane. LDS dest = wave-uniform base + lane*16.
__device__ __forceinline__ void async_copy16(const u16t* g, u16t* l) {
  __builtin_amdgcn_global_load_lds((const __attribute__((address_space(1))) void*)g,
                                   (__attribute__((address_space(3))) void*)l, 16, 0, 0);
}

// ---------------- fused: fp32->bf16 weight cast (blocks 0..16383) + RMSNorm (rest) ----
// Wq/Wk rows are PERMUTED within each head at cast time so that RoPE partners
// (d, d+64) land at columns (p, p+16): p = (d>>4)*32 + (d&15) [+16 for d>=64].
// In the GEMM C-fragment, col and col+16 are the same lane / adjacent nt register,
// so RoPE becomes a pure in-register epilogue op. Q.K dot is invariant (same perm).
__global__ __launch_bounds__(256) void cast_rms_kernel(const float* __restrict__ W0,
                                                       const float* __restrict__ W1,
                                                       const float* __restrict__ W2,
                                                       const float* __restrict__ W3,
                                                       u16t* __restrict__ outw,
                                                       const float* __restrict__ x,
                                                       const float* __restrict__ lnw,
                                                       u16t* __restrict__ h) {
  if (blockIdx.x < 16384) {
    const int idx = blockIdx.x * 256 + threadIdx.x;   // 4M threads, 4 elems each
    const int mat = idx >> 20;
    const size_t off = (size_t)(idx & 0xFFFFF) * 4;
    const float* W = (mat == 0) ? W0 : (mat == 1) ? W1 : (mat == 2) ? W2 : W3;
    const f32x4 v = *(const f32x4*)(W + off);
    size_t dstoff = off;
    if (mat < 2) {   // permute output-feature rows of Wq, Wk
      const int row = (int)(off >> 11);
      const int col = (int)(off & 2047);
      const int d = row & 127;
      const int e = d & 63;
      const int p = ((e >> 4) * 32 + (e & 15)) + ((d >> 6) << 4);
      dstoff = ((size_t)((row & ~127) | p) << 11) | (size_t)col;
    }
    union { u16t s[4]; uint64_t u; } o;
#pragma unroll
    for (int i = 0; i < 4; ++i) o.s[i] = f2bf(v[i]);
    *(uint64_t*)(outw + (size_t)mat * (DM * DM) + dstoff) = o.u;
    return;
  }
  const int row = blockIdx.x - 16384;
  const int tid = threadIdx.x;
  const float* xr = x + (size_t)row * DM + tid * 8;
  f32x4 v0 = *(const f32x4*)(xr);
  f32x4 v1 = *(const f32x4*)(xr + 4);
  float f[8];
#pragma unroll
  for (int i = 0; i < 4; ++i) { f[i] = v0[i]; f[i + 4] = v1[i]; }
  float ss = 0.f;
#pragma unroll
  for (int i = 0; i < 8; ++i) ss += f[i] * f[i];
#pragma unroll
  for (int off = 1; off < 64; off <<= 1) ss += __shfl_xor(ss, off, 64);
  __shared__ float wsum[4];
  if ((tid & 63) == 0) wsum[tid >> 6] = ss;
  __syncthreads();
  float tot = wsum[0] + wsum[1] + wsum[2] + wsum[3];
  float rs = rsqrtf(tot * (1.0f / DM) + 1e-5f);
  f32x4 w0 = *(const f32x4*)(lnw + tid * 8);
  f32x4 w1 = *(const f32x4*)(lnw + tid * 8 + 4);
  u32x4 o;
#pragma unroll
  for (int i = 0; i < 4; ++i) {
    unsigned int lo = f2bf(f[2 * i]     * ((2 * i     < 4) ? w0[2 * i]     : w1[2 * i - 4]) * rs);
    unsigned int hi = f2bf(f[2 * i + 1] * ((2 * i + 1 < 4) ? w0[2 * i + 1] : w1[2 * i - 3]) * rs);
    o[i] = lo | (hi << 16);
  }
  *(u32x4*)(h + (size_t)row * DM + tid * 8) = o;
}

// ---------------- fused QKV GEMM: 128x128x3, A in REGISTERS, B in LDS ----------------
// Round-13 theory: 2-phase QKV was LDS-read-throughput-bound (160 ds_read_b128/CU/
// K-tile ~ 1920 cyc vs 466 cyc MFMA -> predicts the measured 26% MfmaUtil). Fix: A
// fragments load DIRECTLY global->registers (per-lane dwordx4; row = base+i*16+c16,
// k = ks*32+quad*8 is 16B contiguous), double-buffered in named arrays (static
// indexing, rule #20). LDS reads/K-tile/CU: 160 -> 96 (B only); barriers guard only
// B. Same logical global traffic (full 128B k-line consumed). LDS 96 KB.
__global__ __launch_bounds__(512, 2) void gemm_qkv(
    const u16t* __restrict__ A,
    const u16t* __restrict__ B0, const u16t* __restrict__ B1, const u16t* __restrict__ B2,
    u16t* __restrict__ Cq, u16t* __restrict__ Ck, u16t* __restrict__ Cv,
    const float* __restrict__ cosb, const float* __restrict__ sinb) {
  __shared__ u16t Bb[3][2][128 * 64];   // 96 KB
  const int tid  = threadIdx.x;
  const int wave = tid >> 6;
  const int lane = tid & 63;
  const int quad = lane >> 4;
  const int c16  = lane & 15;
  const int h7   = c16 & 7;
  const int wm   = wave >> 2;        // 0..1  (token half: 64 rows)
  const int wn   = wave & 3;         // 0..3  (feature quarter: 32 cols)
  const int bid  = blockIdx.x;
  const int wgid = (bid & 7) * 32 + (bid >> 3);
  const int m0   = (wgid & 15) * 128;
  const int n0   = (wgid >> 4) * 128;

  const int srow = lane >> 3;               // 0..7
  const int sg   = (lane & 7) ^ srow;       // permuted 16B granule
  auto stageB = [&](int d, int k0) {
    const size_t koff = (size_t)k0 + sg * 8;
#pragma unroll
    for (int c = 0; c < 2; ++c) {
      const int rb = wave * 16 + c * 8;     // chunk row base 0..127 (multiple of 8)
      async_copy16(B0 + (size_t)(n0 + rb + srow) * DM + koff, &Bb[0][d][rb * 64]);
      async_copy16(B1 + (size_t)(n0 + rb + srow) * DM + koff, &Bb[1][d][rb * 64]);
      async_copy16(B2 + (size_t)(n0 + rb + srow) * DM + koff, &Bb[2][d][rb * 64]);
    }
  };

  // A direct-to-register: ar[ks*4+i] = A[m0+wm*64+i*16+c16][k0+ks*32+quad*8 ..+7]
  const u16t* Arow = A + (size_t)(m0 + wm * 64 + c16) * DM + quad * 8;
  auto loadA = [&](short8 (&ar)[8], int k0) {
#pragma unroll
    for (int ks = 0; ks < 2; ++ks)
#pragma unroll
      for (int i = 0; i < 4; ++i)
        ar[ks * 4 + i] = *(const short8*)(Arow + (size_t)(i * 16) * DM + k0 + ks * 32);
  };

  const f32x4 fzero = {0.f, 0.f, 0.f, 0.f};
  f32x4 acc[3][4][2];   // [mat][mt][nt] -> 96 VGPR
#pragma unroll
  for (int m = 0; m < 3; ++m)
#pragma unroll
    for (int i = 0; i < 4; ++i)
#pragma unroll
      for (int j = 0; j < 2; ++j) acc[m][i][j] = fzero;

  auto compute = [&](const short8 (&ar)[8], int d) {
#pragma unroll
    for (int ks = 0; ks < 2; ++ks) {
      const int gsw = ((ks * 4 + quad) ^ h7) * 8;
      short8 bfr[3][2];
#pragma unroll
      for (int m = 0; m < 3; ++m)
#pragma unroll
        for (int nt = 0; nt < 2; ++nt)
          bfr[m][nt] = *(const short8*)(&Bb[m][d][0] + (wn * 32 + nt * 16 + c16) * 64 + gsw);
#pragma unroll
      for (int m = 0; m < 3; ++m)
#pragma unroll
        for (int i = 0; i < 4; ++i)
#pragma unroll
          for (int nt = 0; nt < 2; ++nt)
            acc[m][i][nt] =
                __builtin_amdgcn_mfma_f32_16x16x32_bf16(ar[ks * 4 + i], bfr[m][nt],
                                                        acc[m][i][nt], 0, 0, 0);
    }
  };

  short8 arA[8], arB[8];
  loadA(arA, 0);
  stageB(0, 0);
  asm volatile("s_waitcnt vmcnt(0)" ::: "memory");
  __builtin_amdgcn_s_barrier();

  for (int kt = 0; kt < DM / 64; kt += 2) {
    // even tile: compute from (arA, Bb[*][0]); prefetch kt+1 into (arB, Bb[*][1])
    loadA(arB, (kt + 1) * 64);
    stageB(1, (kt + 1) * 64);
    __builtin_amdgcn_s_setprio(1);
    compute(arA, 0);
    __builtin_amdgcn_s_setprio(0);
    asm volatile("s_waitcnt vmcnt(0)" ::: "memory");
    __builtin_amdgcn_s_barrier();
    // odd tile: compute from (arB, Bb[*][1]); prefetch kt+2 into (arA, Bb[*][0])
    if (kt + 2 < DM / 64) { loadA(arA, (kt + 2) * 64); stageB(0, (kt + 2) * 64); }
    __builtin_amdgcn_s_setprio(1);
    compute(arB, 1);
    __builtin_amdgcn_s_setprio(0);
    asm volatile("s_waitcnt vmcnt(0)" ::: "memory");
    __builtin_amdgcn_s_barrier();
  }

  // Q/K with fused RoPE: each wave's cols are (p, p+16) pairs, p = wn*32 + c16.
#pragma unroll
  for (int mat = 0; mat < 2; ++mat) {
    u16t* C = mat ? Ck : Cq;
#pragma unroll
    for (int mt = 0; mt < 4; ++mt) {
#pragma unroll
      for (int r = 0; r < 4; ++r) {
        const int row = m0 + wm * 64 + mt * 16 + quad * 4 + r;   // = token t
        const size_t base = (size_t)row * DM;
        const int col = n0 + wn * 32 + c16;
        const int p = col & 127;
        const int dorig = ((p >> 5) << 4) + c16;
        const float cv = cosb[row * DH + dorig];
        const float sv = sinb[row * DH + dorig];
        const float x1 = acc[mat][mt][0][r];
        const float x2 = acc[mat][mt][1][r];
        C[base + col]      = f2bf(x1 * cv - x2 * sv);
        C[base + col + 16] = f2bf(x2 * cv + x1 * sv);
      }
    }
  }
  // V: transposed store
#pragma unroll
  for (int mt = 0; mt < 4; ++mt) {
#pragma unroll
    for (int r = 0; r < 4; ++r) {
      const int row = m0 + wm * 64 + mt * 16 + quad * 4 + r;
#pragma unroll
      for (int nt = 0; nt < 2; ++nt) {
        const int col = n0 + wn * 32 + nt * 16 + c16;
        Cv[(size_t)col * TS + row] = f2bf(acc[2][mt][nt][r]);
      }
    }
  }
}

// ---------------- out-proj GEMM: 128x128 tile, FULL K, fused residual epilogue --------
// (round-12 verified; frozen as control)
__global__ __launch_bounds__(512, 2) void gemm_out(
    const u16t* __restrict__ A, const u16t* __restrict__ B0,
    const float* __restrict__ xres, const int* __restrict__ am,
    float* __restrict__ out) {
  __shared__ u16t Ab[2][128 * 64];   // 32 KB
  __shared__ u16t Bb[2][128 * 64];   // 32 KB
  const int tid  = threadIdx.x;
  const int wave = tid >> 6;
  const int lane = tid & 63;
  const int quad = lane >> 4;
  const int c16  = lane & 15;
  const int h7   = c16 & 7;
  const int wm   = wave >> 2;        // 0..1  (row half: 64 rows)
  const int wn   = wave & 3;         // 0..3  (col quarter: 32 cols)
  const int bid  = blockIdx.x;
  const int wgid = (bid & 7) * 32 + (bid >> 3);   // XCD swizzle, bijective at 256
  const int m0   = (wgid & 15) * 128;
  const int n0   = (wgid >> 4) * 128;

  const int srow = lane >> 3;
  const int sg   = (lane & 7) ^ srow;
  auto stage = [&](int d, int k0) {
    const size_t koff = (size_t)k0 + sg * 8;
#pragma unroll
    for (int c = 0; c < 2; ++c) {
      const int rb = wave * 16 + c * 8;
      async_copy16(A  + (size_t)(m0 + rb + srow) * DM + koff, &Ab[d][rb * 64]);
      async_copy16(B0 + (size_t)(n0 + rb + srow) * DM + koff, &Bb[d][rb * 64]);
    }
  };

  const f32x4 fzero = {0.f, 0.f, 0.f, 0.f};
  f32x4 acc[4][2];
#pragma unroll
  for (int i = 0; i < 4; ++i)
#pragma unroll
    for (int j = 0; j < 2; ++j) acc[i][j] = fzero;

  stage(0, 0);
  asm volatile("s_waitcnt vmcnt(0)" ::: "memory");
  __builtin_amdgcn_s_barrier();

  for (int kt = 0; kt < DM / 64; ++kt) {
    const int cur = kt & 1;
    if (kt + 1 < DM / 64) stage(cur ^ 1, (kt + 1) * 64);
    const u16t* Abuf = Ab[cur];
    const u16t* Bbuf = Bb[cur];
    __builtin_amdgcn_s_setprio(1);
#pragma unroll
    for (int ks = 0; ks < 2; ++ks) {
      const int gsw = ((ks * 4 + quad) ^ h7) * 8;
      short8 af[4], bfr[2];
#pragma unroll
      for (int i = 0; i < 4; ++i)
        af[i] = *(const short8*)(Abuf + (wm * 64 + i * 16 + c16) * 64 + gsw);
#pragma unroll
      for (int nt = 0; nt < 2; ++nt)
        bfr[nt] = *(const short8*)(Bbuf + (wn * 32 + nt * 16 + c16) * 64 + gsw);
#pragma unroll
      for (int i = 0; i < 4; ++i)
#pragma unroll
        for (int nt = 0; nt < 2; ++nt)
          acc[i][nt] =
              __builtin_amdgcn_mfma_f32_16x16x32_bf16(af[i], bfr[nt], acc[i][nt], 0, 0, 0);
    }
    __builtin_amdgcn_s_setprio(0);
    asm volatile("s_waitcnt vmcnt(0)" ::: "memory");
    __builtin_amdgcn_s_barrier();
  }

  // fused residual + row-mask epilogue, fp32 store direct to output
#pragma unroll
  for (int mt = 0; mt < 4; ++mt) {
#pragma unroll
    for (int r = 0; r < 4; ++r) {
      const int row = m0 + wm * 64 + mt * 16 + quad * 4 + r;
      const float mk = (am[row] != 0) ? 1.f : 0.f;
      const size_t base = (size_t)row * DM;
#pragma unroll
      for (int nt = 0; nt < 2; ++nt) {
        const int col = n0 + wn * 32 + nt * 16 + c16;
        out[base + col] = xres[base + col] + mk * acc[mt][nt][r];
      }
    }
  }
}

// ---------------- Flash attention (causal), SWAPPED QK^T, in-register softmax ----------
// (round-13 verified: total 280.4, absmax unchanged — frozen as control)
__global__ __launch_bounds__(256) void attn_kernel(const u16t* __restrict__ Q,
                                                   const u16t* __restrict__ K,
                                                   const u16t* __restrict__ Vt,
                                                   const int* __restrict__ am,
                                                   u16t* __restrict__ O) {
  __shared__ u16t Klds[128 * 128];   // [key][d], swizzled granules, 32 KB
  __shared__ u16t Vlds[128 * 128];   // [d][key], swizzled granules, 32 KB
  __shared__ u16t Plds[4][2048];     // per-wave P (packed u32) / O-transpose, 16 KB
  const int wave = threadIdx.x >> 6;
  const int lane = threadIdx.x & 63;
  const int x    = blockIdx.x;
  const int half = x >> 8;                  // 0: qt 31..16, 1: qt 0..15
  const int idx  = x & 255;
  const int head = idx & (NH - 1);
  const int grp  = idx >> 4;                // 0..15
  const int qt   = half ? grp : (TS / 64 - 1 - grp);
  const int q0   = qt * 64 + wave * 16;
  const int quad = lane >> 4;
  const int c16  = lane & 15;
  const u16t* Qh  = Q + head * DH;
  const u16t* Kh  = K + head * DH;
  const u16t* Vth = Vt + (size_t)head * DH * TS;
  u16t* Pw = Plds[wave];
  uint32_t* Pw32 = (uint32_t*)Pw;
  const int pswz = (c16 & 7) << 2;          // u32-level XOR (bits 2-4), b128-safe

  const int row_s = (lane >> 4);    // 0..3 row within chunk
  const int g_s   = (lane & 15);    // granule slot

  short8 qf[4];
#pragma unroll
  for (int dc = 0; dc < 4; ++dc)
    qf[dc] = *(const short8*)(Qh + (size_t)(q0 + c16) * DM + dc * 32 + quad * 8);

  const f32x4 fzero = {0.f, 0.f, 0.f, 0.f};
  float m_run = -1e30f, l_run = 0.f;
  f32x4 o_acc[8];                   // out^T[d = mt*16+quad*4+r][q = c16]
#pragma unroll
  for (int mt = 0; mt < 8; ++mt) o_acc[mt] = fzero;

  const float scale = 0.08838834764831845f;  // 1/sqrt(128)
  const int ntiles = (qt * 64 + 191) >> 7;   // 128-wide tiles covering keys 0..q0+63
  const int qrow = q0 + c16;

  for (int kt = 0; kt < ntiles; ++kt) {
    const int k0 = kt * 128;
    __syncthreads();
#pragma unroll
    for (int c = 0; c < 8; ++c) {
      const int ch = wave * 8 + c;
      const int r  = 4 * ch + row_s;           // 0..127
      const int g  = g_s ^ (r & 15);
      async_copy16(Kh + (size_t)(k0 + r) * DM + g * 8, Klds + ch * 512);
      async_copy16(Vth + (size_t)r * TS + k0 + g * 8, Vlds + ch * 512);
    }
    __syncthreads();

    // S^T = K . Q^T : lane holds S^T[key = k0+ns*16+quad*4+r][q = qrow]
    f32x4 s[8];
#pragma unroll
    for (int ns = 0; ns < 8; ++ns) {
      f32x4 sa = fzero;
      const int rr = ns * 16 + c16;
#pragma unroll
      for (int dc = 0; dc < 4; ++dc) {
        short8 kf = *(const short8*)(Klds + rr * 128 + (((dc * 4 + quad) ^ c16) * 8));
        sa = __builtin_amdgcn_mfma_f32_16x16x32_bf16(kf, qf[dc], sa, 0, 0, 0);
      }
      s[ns] = sa;
    }

    // mask + in-lane max over this q-row's 32 keys
    float pv[8][4];
    float tmax = -1e30f;
#pragma unroll
    for (int ns = 0; ns < 8; ++ns) {
      const i32x4 a4 = *(const i32x4*)(am + k0 + ns * 16 + quad * 4);
#pragma unroll
      for (int r = 0; r < 4; ++r) {
        const int key = k0 + ns * 16 + quad * 4 + r;
        float v = s[ns][r] * scale;
        if (key > qrow || a4[r] == 0) v = -1e30f;
        pv[ns][r] = v;
        tmax = fmaxf(tmax, v);
      }
    }
    // full-row reduce across the 4 quads holding this q-row
    tmax = fmaxf(tmax, __shfl_xor(tmax, 16, 64));
    tmax = fmaxf(tmax, __shfl_xor(tmax, 32, 64));
    const float mn = fmaxf(m_run, tmax);
    const float alpha = __expf(m_run - mn);
    m_run = mn;
    float rs = 0.f;
#pragma unroll
    for (int ns = 0; ns < 8; ++ns)
#pragma unroll
      for (int r = 0; r < 4; ++r) {
        const float e = __expf(pv[ns][r] - mn);
        pv[ns][r] = e;
        rs += e;
      }
    rs += __shfl_xor(rs, 16, 64);
    rs += __shfl_xor(rs, 32, 64);
    l_run = l_run * alpha + rs;

    // pack P to bf16 pairs; store as [q=c16 row][key-pair], XOR-swizzled u32 layout.
    // logical u32 L = ns*8 + quad*2 + i covers keys ns*16+quad*4+2i, +2i+1.
#pragma unroll
    for (int ns = 0; ns < 8; ++ns)
#pragma unroll
      for (int i = 0; i < 2; ++i) {
        uint32_t pk;
        asm("v_cvt_pk_bf16_f32 %0, %1, %2"
            : "=v"(pk) : "v"(pv[ns][2 * i]), "v"(pv[ns][2 * i + 1]));
        Pw32[c16 * 64 + ((ns * 8 + quad * 2 + i) ^ pswz)] = pk;
      }
    asm volatile("s_waitcnt lgkmcnt(0)" ::: "memory");
    // B-fragments: pa[kb] = P[q=c16][keys kb*32 + quad*8 + 0..7]
    short8 pa[4];
#pragma unroll
    for (int kb = 0; kb < 4; ++kb)
      pa[kb] = *(const short8*)(Pw32 + c16 * 64 + ((kb * 16 + quad * 4) ^ pswz));

    // rescale + PV: o_acc[mt] = mfma(A = Vt[d-rows], B = pa)
#pragma unroll
    for (int mt = 0; mt < 8; ++mt)
#pragma unroll
      for (int r = 0; r < 4; ++r) o_acc[mt][r] *= alpha;
#pragma unroll
    for (int mt = 0; mt < 8; ++mt) {
      const int rrv = mt * 16 + c16;           // d-row
#pragma unroll
      for (int kb = 0; kb < 4; ++kb) {
        short8 vf = *(const short8*)(Vlds + rrv * 128 + (((kb * 4 + quad) ^ c16) * 8));
        o_acc[mt] = __builtin_amdgcn_mfma_f32_16x16x32_bf16(vf, pa[kb], o_acc[mt], 0, 0, 0);
      }
    }
  }

  // epilogue: normalize, transpose via per-wave LDS, coalesced 16B stores
  const float inv = 1.0f / fmaxf(l_run, 1e-20f);
#pragma unroll
  for (int mt = 0; mt < 8; ++mt)
#pragma unroll
    for (int r = 0; r < 4; ++r) {
      const int d = mt * 16 + quad * 4 + r;
      Pw[c16 * 128 + d] = f2bf(o_acc[mt][r] * inv);
    }
  asm volatile("s_waitcnt lgkmcnt(0)" ::: "memory");
#pragma unroll
  for (int p = 0; p < 4; ++p) {
    const int row = p * 4 + quad;              // q-local 0..15
    short8 v = *(const short8*)(Pw + row * 128 + c16 * 8);
    *(short8*)(O + (size_t)(q0 + row) * DM + head * DH + c16 * 8) = v;
  }
}

extern "C" void kernel_launch(void* const* d_in, const int* in_sizes, int n_in,
                              void* d_out, int out_size, void* d_ws, size_t ws_size,
                              hipStream_t stream) {
  const float* x    = (const float*)d_in[0];
  const float* cosb = (const float*)d_in[1];
  const float* sinb = (const float*)d_in[2];
  const int*   am   = (const int*)d_in[3];
  const float* lnw  = (const float*)d_in[4];
  const float* Wq   = (const float*)d_in[5];
  const float* Wk   = (const float*)d_in[6];
  const float* Wv   = (const float*)d_in[7];
  const float* Wo   = (const float*)d_in[8];
  float* out = (float*)d_out;

  u16t* h    = (u16t*)d_ws;                 // (T, D) bf16   [0, 8 MB)
  u16t* Q    = h + (size_t)TS * DM;         //               [8, 16)
  u16t* K    = Q + (size_t)TS * DM;         //               [16, 24)
  u16t* Vt   = K + (size_t)TS * DM;         //               [24, 32)
  u16t* attn = Vt + (size_t)TS * DM;        //               [32, 40)
  u16t* Wb   = attn + (size_t)TS * DM;      // 4 x (D, D)    [40, 72)
  u16t* Wqb = Wb;
  u16t* Wkb = Wb + (size_t)DM * DM;
  u16t* Wvb = Wb + 2 * (size_t)DM * DM;
  u16t* Wob = Wb + 3 * (size_t)DM * DM;

  cast_rms_kernel<<<16384 + TS, 256, 0, stream>>>(Wq, Wk, Wv, Wo, Wb, x, lnw, h);
  // fused QKV: 16x16 tiles = 256 blocks (1/CU), A-in-registers, B-in-LDS
  gemm_qkv<<<256, 512, 0, stream>>>(h, Wqb, Wkb, Wvb, Q, K, Vt, cosb, sinb);
  attn_kernel<<<NH * (TS / 64), 256, 0, stream>>>(Q, K, Vt, am, attn);
  // out-proj: 128x128 tiles, full K, fused residual+mask epilogue -> out (fp32)
  gemm_out<<<256, 512, 0, stream>>>(attn, Wob, x, am, out);
}

// Round 17
// 266.831 us; speedup vs baseline: 1.1762x; 1.1762x over previous
//
#include <hip/hip_runtime.h>
#include <stdint.h>

#define TS 2048
#define DM 2048
#define NH 16
#define DH 128

typedef unsigned short u16t;
typedef __attribute__((ext_vector_type(8))) short short8;
typedef __attribute__((ext_vector_type(4))) float f32x4;
typedef __attribute__((ext_vector_type(4))) unsigned int u32x4;
typedef __attribute__((ext_vector_type(4))) int i32x4;

__device__ __forceinline__ float bf2f(u16t b) {
  return __uint_as_float(((unsigned int)b) << 16);
}
__device__ __forceinline__ u16t f2bf(float f) {
  unsigned int u = __float_as_uint(f);
  u += 0x7FFFu + ((u >> 16) & 1u);   // round-to-nearest-even
  return (u16t)(u >> 16);
}

// async global->LDS, 16B per lane. LDS dest = wave-uniform base + lane*16.
__device__ __forceinline__ void async_copy16(const u16t* g, u16t* l) {
  __builtin_amdgcn_global_load_lds((const __attribute__((address_space(1))) void*)g,
                                   (__attribute__((address_space(3))) void*)l, 16, 0, 0);
}

// ---------------- fused: fp32->bf16 weight cast (blocks 0..16383) + RMSNorm (rest) ----
// Wq/Wk rows are PERMUTED within each head at cast time so that RoPE partners
// (d, d+64) land at columns (p, p+16): p = (d>>4)*32 + (d&15) [+16 for d>=64].
// In the GEMM C-fragment, col and col+16 are the same lane / adjacent nt register,
// so RoPE becomes a pure in-register epilogue op. Q.K dot is invariant (same perm).
__global__ __launch_bounds__(256) void cast_rms_kernel(const float* __restrict__ W0,
                                                       const float* __restrict__ W1,
                                                       const float* __restrict__ W2,
                                                       const float* __restrict__ W3,
                                                       u16t* __restrict__ outw,
                                                       const float* __restrict__ x,
                                                       const float* __restrict__ lnw,
                                                       u16t* __restrict__ h) {
  if (blockIdx.x < 16384) {
    const int idx = blockIdx.x * 256 + threadIdx.x;   // 4M threads, 4 elems each
    const int mat = idx >> 20;
    const size_t off = (size_t)(idx & 0xFFFFF) * 4;
    const float* W = (mat == 0) ? W0 : (mat == 1) ? W1 : (mat == 2) ? W2 : W3;
    const f32x4 v = *(const f32x4*)(W + off);
    size_t dstoff = off;
    if (mat < 2) {   // permute output-feature rows of Wq, Wk
      const int row = (int)(off >> 11);
      const int col = (int)(off & 2047);
      const int d = row & 127;
      const int e = d & 63;
      const int p = ((e >> 4) * 32 + (e & 15)) + ((d >> 6) << 4);
      dstoff = ((size_t)((row & ~127) | p) << 11) | (size_t)col;
    }
    union { u16t s[4]; uint64_t u; } o;
#pragma unroll
    for (int i = 0; i < 4; ++i) o.s[i] = f2bf(v[i]);
    *(uint64_t*)(outw + (size_t)mat * (DM * DM) + dstoff) = o.u;
    return;
  }
  const int row = blockIdx.x - 16384;
  const int tid = threadIdx.x;
  const float* xr = x + (size_t)row * DM + tid * 8;
  f32x4 v0 = *(const f32x4*)(xr);
  f32x4 v1 = *(const f32x4*)(xr + 4);
  float f[8];
#pragma unroll
  for (int i = 0; i < 4; ++i) { f[i] = v0[i]; f[i + 4] = v1[i]; }
  float ss = 0.f;
#pragma unroll
  for (int i = 0; i < 8; ++i) ss += f[i] * f[i];
#pragma unroll
  for (int off = 1; off < 64; off <<= 1) ss += __shfl_xor(ss, off, 64);
  __shared__ float wsum[4];
  if ((tid & 63) == 0) wsum[tid >> 6] = ss;
  __syncthreads();
  float tot = wsum[0] + wsum[1] + wsum[2] + wsum[3];
  float rs = rsqrtf(tot * (1.0f / DM) + 1e-5f);
  f32x4 w0 = *(const f32x4*)(lnw + tid * 8);
  f32x4 w1 = *(const f32x4*)(lnw + tid * 8 + 4);
  u32x4 o;
#pragma unroll
  for (int i = 0; i < 4; ++i) {
    unsigned int lo = f2bf(f[2 * i]     * ((2 * i     < 4) ? w0[2 * i]     : w1[2 * i - 4]) * rs);
    unsigned int hi = f2bf(f[2 * i + 1] * ((2 * i + 1 < 4) ? w0[2 * i + 1] : w1[2 * i - 3]) * rs);
    o[i] = lo | (hi << 16);
  }
  *(u32x4*)(h + (size_t)row * DM + tid * 8) = o;
}

// ---------------- fused QKV GEMM: 128tok x 64feat x 3 mats, 2 blocks/CU --------------
// Round-14 post-mortem: A-in-registers regressed (scattered per-lane VMEM); and the
// cycle accounting (LDS ~640cy + MFMA ~466cy + VALU ~800cy vs measured ~5925cy/K-tile)
// shows the 1-block/CU structure is LATENCY/SYNC-bound, not BW-bound. Fix: back to
// verified global_load_lds staging, tile shrunk to 128x64x3 so LDS = A 32KB + B 48KB
// = 80KB -> 2 co-resident blocks/CU (m114: blocks hide each other's barrier drains),
// grid 16x32 = 512, 16 waves/CU (4/SIMD, 2x occupancy). Waves 4m x 2n, 32x32x3 each.
// 2-phase schedule + granule swizzle (0-conflict) + RoPE/Vt epilogues unchanged.
__global__ __launch_bounds__(512, 4) void gemm_qkv(
    const u16t* __restrict__ A,
    const u16t* __restrict__ B0, const u16t* __restrict__ B1, const u16t* __restrict__ B2,
    u16t* __restrict__ Cq, u16t* __restrict__ Ck, u16t* __restrict__ Cv,
    const float* __restrict__ cosb, const float* __restrict__ sinb) {
  __shared__ u16t Ab[2][128 * 64];      // 32 KB
  __shared__ u16t Bb[3][2][64 * 64];    // 48 KB
  const int tid  = threadIdx.x;
  const int wave = tid >> 6;
  const int lane = tid & 63;
  const int quad = lane >> 4;
  const int c16  = lane & 15;
  const int h7   = c16 & 7;
  const int wm   = wave >> 1;        // 0..3  (32-token slice)
  const int wn   = wave & 1;         // 0..1  (32-feature slice)
  const int bid  = blockIdx.x;
  const int wgid = (bid & 7) * 64 + (bid >> 3);   // XCD swizzle, bijective at 512
  const int m0   = (wgid & 15) * 128;
  const int n0   = (wgid >> 4) * 64;

  const int srow = lane >> 3;               // 0..7
  const int sg   = (lane & 7) ^ srow;       // permuted 16B granule (involution)
  auto stage = [&](int d, int k0) {
    const size_t koff = (size_t)k0 + sg * 8;
#pragma unroll
    for (int c = 0; c < 2; ++c) {           // A: 2 chunks/wave (16 rows)
      const int rb = wave * 16 + c * 8;
      async_copy16(A + (size_t)(m0 + rb + srow) * DM + koff, &Ab[d][rb * 64]);
    }
    const int rbB = wave * 8;               // B: 1 chunk/wave/mat (8 rows)
    async_copy16(B0 + (size_t)(n0 + rbB + srow) * DM + koff, &Bb[0][d][rbB * 64]);
    async_copy16(B1 + (size_t)(n0 + rbB + srow) * DM + koff, &Bb[1][d][rbB * 64]);
    async_copy16(B2 + (size_t)(n0 + rbB + srow) * DM + koff, &Bb[2][d][rbB * 64]);
  };

  const f32x4 fzero = {0.f, 0.f, 0.f, 0.f};
  f32x4 acc[3][2][2];   // [mat][mt][nt] -> 48 VGPR
#pragma unroll
  for (int m = 0; m < 3; ++m)
#pragma unroll
    for (int i = 0; i < 2; ++i)
#pragma unroll
      for (int j = 0; j < 2; ++j) acc[m][i][j] = fzero;

  stage(0, 0);
  asm volatile("s_waitcnt vmcnt(0)" ::: "memory");
  __builtin_amdgcn_s_barrier();

  for (int kt = 0; kt < DM / 64; ++kt) {
    const int cur = kt & 1;
    if (kt + 1 < DM / 64) stage(cur ^ 1, (kt + 1) * 64);   // prefetch under compute
    const u16t* Abuf = Ab[cur];
    __builtin_amdgcn_s_setprio(1);
#pragma unroll
    for (int ks = 0; ks < 2; ++ks) {       // two K=32 halves
      const int gsw = ((ks * 4 + quad) ^ h7) * 8;
      short8 af[2], bfr[3][2];
#pragma unroll
      for (int i = 0; i < 2; ++i)
        af[i] = *(const short8*)(Abuf + (wm * 32 + i * 16 + c16) * 64 + gsw);
#pragma unroll
      for (int m = 0; m < 3; ++m)
#pragma unroll
        for (int nt = 0; nt < 2; ++nt)
          bfr[m][nt] = *(const short8*)(&Bb[m][cur][0] + (wn * 32 + nt * 16 + c16) * 64 + gsw);
#pragma unroll
      for (int m = 0; m < 3; ++m)
#pragma unroll
        for (int i = 0; i < 2; ++i)
#pragma unroll
          for (int nt = 0; nt < 2; ++nt)
            acc[m][i][nt] =
                __builtin_amdgcn_mfma_f32_16x16x32_bf16(af[i], bfr[m][nt], acc[m][i][nt], 0, 0, 0);
    }
    __builtin_amdgcn_s_setprio(0);
    asm volatile("s_waitcnt vmcnt(0)" ::: "memory");
    __builtin_amdgcn_s_barrier();
  }

  // Q/K with fused RoPE: each wave's cols are (p, p+16) pairs, p = col & 127
  // (bit4 of col is 0: n0 % 64 == 0, wn*32 keeps bit4 clear, c16 < 16).
#pragma unroll
  for (int mat = 0; mat < 2; ++mat) {
    u16t* C = mat ? Ck : Cq;
#pragma unroll
    for (int mt = 0; mt < 2; ++mt) {
#pragma unroll
      for (int r = 0; r < 4; ++r) {
        const int row = m0 + wm * 32 + mt * 16 + quad * 4 + r;   // = token t
        const size_t base = (size_t)row * DM;
        const int col = n0 + wn * 32 + c16;
        const int p = col & 127;
        const int dorig = ((p >> 5) << 4) + c16;
        const float cv = cosb[row * DH + dorig];
        const float sv = sinb[row * DH + dorig];
        const float x1 = acc[mat][mt][0][r];
        const float x2 = acc[mat][mt][1][r];
        C[base + col]      = f2bf(x1 * cv - x2 * sv);
        C[base + col + 16] = f2bf(x2 * cv + x1 * sv);
      }
    }
  }
  // V: transposed store
#pragma unroll
  for (int mt = 0; mt < 2; ++mt) {
#pragma unroll
    for (int r = 0; r < 4; ++r) {
      const int row = m0 + wm * 32 + mt * 16 + quad * 4 + r;
#pragma unroll
      for (int nt = 0; nt < 2; ++nt) {
        const int col = n0 + wn * 32 + nt * 16 + c16;
        Cv[(size_t)col * TS + row] = f2bf(acc[2][mt][nt][r]);
      }
    }
  }
}

// ---------------- out-proj GEMM: 128x128 tile, FULL K, fused residual epilogue --------
// (round-12 verified; frozen as control)
__global__ __launch_bounds__(512, 2) void gemm_out(
    const u16t* __restrict__ A, const u16t* __restrict__ B0,
    const float* __restrict__ xres, const int* __restrict__ am,
    float* __restrict__ out) {
  __shared__ u16t Ab[2][128 * 64];   // 32 KB
  __shared__ u16t Bb[2][128 * 64];   // 32 KB
  const int tid  = threadIdx.x;
  const int wave = tid >> 6;
  const int lane = tid & 63;
  const int quad = lane >> 4;
  const int c16  = lane & 15;
  const int h7   = c16 & 7;
  const int wm   = wave >> 2;        // 0..1  (row half: 64 rows)
  const int wn   = wave & 3;         // 0..3  (col quarter: 32 cols)
  const int bid  = blockIdx.x;
  const int wgid = (bid & 7) * 32 + (bid >> 3);   // XCD swizzle, bijective at 256
  const int m0   = (wgid & 15) * 128;
  const int n0   = (wgid >> 4) * 128;

  const int srow = lane >> 3;
  const int sg   = (lane & 7) ^ srow;
  auto stage = [&](int d, int k0) {
    const size_t koff = (size_t)k0 + sg * 8;
#pragma unroll
    for (int c = 0; c < 2; ++c) {
      const int rb = wave * 16 + c * 8;
      async_copy16(A  + (size_t)(m0 + rb + srow) * DM + koff, &Ab[d][rb * 64]);
      async_copy16(B0 + (size_t)(n0 + rb + srow) * DM + koff, &Bb[d][rb * 64]);
    }
  };

  const f32x4 fzero = {0.f, 0.f, 0.f, 0.f};
  f32x4 acc[4][2];
#pragma unroll
  for (int i = 0; i < 4; ++i)
#pragma unroll
    for (int j = 0; j < 2; ++j) acc[i][j] = fzero;

  stage(0, 0);
  asm volatile("s_waitcnt vmcnt(0)" ::: "memory");
  __builtin_amdgcn_s_barrier();

  for (int kt = 0; kt < DM / 64; ++kt) {
    const int cur = kt & 1;
    if (kt + 1 < DM / 64) stage(cur ^ 1, (kt + 1) * 64);
    const u16t* Abuf = Ab[cur];
    const u16t* Bbuf = Bb[cur];
    __builtin_amdgcn_s_setprio(1);
#pragma unroll
    for (int ks = 0; ks < 2; ++ks) {
      const int gsw = ((ks * 4 + quad) ^ h7) * 8;
      short8 af[4], bfr[2];
#pragma unroll
      for (int i = 0; i < 4; ++i)
        af[i] = *(const short8*)(Abuf + (wm * 64 + i * 16 + c16) * 64 + gsw);
#pragma unroll
      for (int nt = 0; nt < 2; ++nt)
        bfr[nt] = *(const short8*)(Bbuf + (wn * 32 + nt * 16 + c16) * 64 + gsw);
#pragma unroll
      for (int i = 0; i < 4; ++i)
#pragma unroll
        for (int nt = 0; nt < 2; ++nt)
          acc[i][nt] =
              __builtin_amdgcn_mfma_f32_16x16x32_bf16(af[i], bfr[nt], acc[i][nt], 0, 0, 0);
    }
    __builtin_amdgcn_s_setprio(0);
    asm volatile("s_waitcnt vmcnt(0)" ::: "memory");
    __builtin_amdgcn_s_barrier();
  }

  // fused residual + row-mask epilogue, fp32 store direct to output
#pragma unroll
  for (int mt = 0; mt < 4; ++mt) {
#pragma unroll
    for (int r = 0; r < 4; ++r) {
      const int row = m0 + wm * 64 + mt * 16 + quad * 4 + r;
      const float mk = (am[row] != 0) ? 1.f : 0.f;
      const size_t base = (size_t)row * DM;
#pragma unroll
      for (int nt = 0; nt < 2; ++nt) {
        const int col = n0 + wn * 32 + nt * 16 + c16;
        out[base + col] = xres[base + col] + mk * acc[mt][nt][r];
      }
    }
  }
}

// ---------------- Flash attention (causal), SWAPPED QK^T, in-register softmax ----------
// (round-13 verified: total 280.4, absmax unchanged — frozen as control)
__global__ __launch_bounds__(256) void attn_kernel(const u16t* __restrict__ Q,
                                                   const u16t* __restrict__ K,
                                                   const u16t* __restrict__ Vt,
                                                   const int* __restrict__ am,
                                                   u16t* __restrict__ O) {
  __shared__ u16t Klds[128 * 128];   // [key][d], swizzled granules, 32 KB
  __shared__ u16t Vlds[128 * 128];   // [d][key], swizzled granules, 32 KB
  __shared__ u16t Plds[4][2048];     // per-wave P (packed u32) / O-transpose, 16 KB
  const int wave = threadIdx.x >> 6;
  const int lane = threadIdx.x & 63;
  const int x    = blockIdx.x;
  const int half = x >> 8;                  // 0: qt 31..16, 1: qt 0..15
  const int idx  = x & 255;
  const int head = idx & (NH - 1);
  const int grp  = idx >> 4;                // 0..15
  const int qt   = half ? grp : (TS / 64 - 1 - grp);
  const int q0   = qt * 64 + wave * 16;
  const int quad = lane >> 4;
  const int c16  = lane & 15;
  const u16t* Qh  = Q + head * DH;
  const u16t* Kh  = K + head * DH;
  const u16t* Vth = Vt + (size_t)head * DH * TS;
  u16t* Pw = Plds[wave];
  uint32_t* Pw32 = (uint32_t*)Pw;
  const int pswz = (c16 & 7) << 2;          // u32-level XOR (bits 2-4), b128-safe

  const int row_s = (lane >> 4);    // 0..3 row within chunk
  const int g_s   = (lane & 15);    // granule slot

  short8 qf[4];
#pragma unroll
  for (int dc = 0; dc < 4; ++dc)
    qf[dc] = *(const short8*)(Qh + (size_t)(q0 + c16) * DM + dc * 32 + quad * 8);

  const f32x4 fzero = {0.f, 0.f, 0.f, 0.f};
  float m_run = -1e30f, l_run = 0.f;
  f32x4 o_acc[8];                   // out^T[d = mt*16+quad*4+r][q = c16]
#pragma unroll
  for (int mt = 0; mt < 8; ++mt) o_acc[mt] = fzero;

  const float scale = 0.08838834764831845f;  // 1/sqrt(128)
  const int ntiles = (qt * 64 + 191) >> 7;   // 128-wide tiles covering keys 0..q0+63
  const int qrow = q0 + c16;

  for (int kt = 0; kt < ntiles; ++kt) {
    const int k0 = kt * 128;
    __syncthreads();
#pragma unroll
    for (int c = 0; c < 8; ++c) {
      const int ch = wave * 8 + c;
      const int r  = 4 * ch + row_s;           // 0..127
      const int g  = g_s ^ (r & 15);
      async_copy16(Kh + (size_t)(k0 + r) * DM + g * 8, Klds + ch * 512);
      async_copy16(Vth + (size_t)r * TS + k0 + g * 8, Vlds + ch * 512);
    }
    __syncthreads();

    // S^T = K . Q^T : lane holds S^T[key = k0+ns*16+quad*4+r][q = qrow]
    f32x4 s[8];
#pragma unroll
    for (int ns = 0; ns < 8; ++ns) {
      f32x4 sa = fzero;
      const int rr = ns * 16 + c16;
#pragma unroll
      for (int dc = 0; dc < 4; ++dc) {
        short8 kf = *(const short8*)(Klds + rr * 128 + (((dc * 4 + quad) ^ c16) * 8));
        sa = __builtin_amdgcn_mfma_f32_16x16x32_bf16(kf, qf[dc], sa, 0, 0, 0);
      }
      s[ns] = sa;
    }

    // mask + in-lane max over this q-row's 32 keys
    float pv[8][4];
    float tmax = -1e30f;
#pragma unroll
    for (int ns = 0; ns < 8; ++ns) {
      const i32x4 a4 = *(const i32x4*)(am + k0 + ns * 16 + quad * 4);
#pragma unroll
      for (int r = 0; r < 4; ++r) {
        const int key = k0 + ns * 16 + quad * 4 + r;
        float v = s[ns][r] * scale;
        if (key > qrow || a4[r] == 0) v = -1e30f;
        pv[ns][r] = v;
        tmax = fmaxf(tmax, v);
      }
    }
    // full-row reduce across the 4 quads holding this q-row
    tmax = fmaxf(tmax, __shfl_xor(tmax, 16, 64));
    tmax = fmaxf(tmax, __shfl_xor(tmax, 32, 64));
    const float mn = fmaxf(m_run, tmax);
    const float alpha = __expf(m_run - mn);
    m_run = mn;
    float rs = 0.f;
#pragma unroll
    for (int ns = 0; ns < 8; ++ns)
#pragma unroll
      for (int r = 0; r < 4; ++r) {
        const float e = __expf(pv[ns][r] - mn);
        pv[ns][r] = e;
        rs += e;
      }
    rs += __shfl_xor(rs, 16, 64);
    rs += __shfl_xor(rs, 32, 64);
    l_run = l_run * alpha + rs;

    // pack P to bf16 pairs; store as [q=c16 row][key-pair], XOR-swizzled u32 layout.
    // logical u32 L = ns*8 + quad*2 + i covers keys ns*16+quad*4+2i, +2i+1.
#pragma unroll
    for (int ns = 0; ns < 8; ++ns)
#pragma unroll
      for (int i = 0; i < 2; ++i) {
        uint32_t pk;
        asm("v_cvt_pk_bf16_f32 %0, %1, %2"
            : "=v"(pk) : "v"(pv[ns][2 * i]), "v"(pv[ns][2 * i + 1]));
        Pw32[c16 * 64 + ((ns * 8 + quad * 2 + i) ^ pswz)] = pk;
      }
    asm volatile("s_waitcnt lgkmcnt(0)" ::: "memory");
    // B-fragments: pa[kb] = P[q=c16][keys kb*32 + quad*8 + 0..7]
    short8 pa[4];
#pragma unroll
    for (int kb = 0; kb < 4; ++kb)
      pa[kb] = *(const short8*)(Pw32 + c16 * 64 + ((kb * 16 + quad * 4) ^ pswz));

    // rescale + PV: o_acc[mt] = mfma(A = Vt[d-rows], B = pa)
#pragma unroll
    for (int mt = 0; mt < 8; ++mt)
#pragma unroll
      for (int r = 0; r < 4; ++r) o_acc[mt][r] *= alpha;
#pragma unroll
    for (int mt = 0; mt < 8; ++mt) {
      const int rrv = mt * 16 + c16;           // d-row
#pragma unroll
      for (int kb = 0; kb < 4; ++kb) {
        short8 vf = *(const short8*)(Vlds + rrv * 128 + (((kb * 4 + quad) ^ c16) * 8));
        o_acc[mt] = __builtin_amdgcn_mfma_f32_16x16x32_bf16(vf, pa[kb], o_acc[mt], 0, 0, 0);
      }
    }
  }

  // epilogue: normalize, transpose via per-wave LDS, coalesced 16B stores
  const float inv = 1.0f / fmaxf(l_run, 1e-20f);
#pragma unroll
  for (int mt = 0; mt < 8; ++mt)
#pragma unroll
    for (int r = 0; r < 4; ++r) {
      const int d = mt * 16 + quad * 4 + r;
      Pw[c16 * 128 + d] = f2bf(o_acc[mt][r] * inv);
    }
  asm volatile("s_waitcnt lgkmcnt(0)" ::: "memory");
#pragma unroll
  for (int p = 0; p < 4; ++p) {
    const int row = p * 4 + quad;              // q-local 0..15
    short8 v = *(const short8*)(Pw + row * 128 + c16 * 8);
    *(short8*)(O + (size_t)(q0 + row) * DM + head * DH + c16 * 8) = v;
  }
}

extern "C" void kernel_launch(void* const* d_in, const int* in_sizes, int n_in,
                              void* d_out, int out_size, void* d_ws, size_t ws_size,
                              hipStream_t stream) {
  const float* x    = (const float*)d_in[0];
  const float* cosb = (const float*)d_in[1];
  const float* sinb = (const float*)d_in[2];
  const int*   am   = (const int*)d_in[3];
  const float* lnw  = (const float*)d_in[4];
  const float* Wq   = (const float*)d_in[5];
  const float* Wk   = (const float*)d_in[6];
  const float* Wv   = (const float*)d_in[7];
  const float* Wo   = (const float*)d_in[8];
  float* out = (float*)d_out;

  u16t* h    = (u16t*)d_ws;                 // (T, D) bf16   [0, 8 MB)
  u16t* Q    = h + (size_t)TS * DM;         //               [8, 16)
  u16t* K    = Q + (size_t)TS * DM;         //               [16, 24)
  u16t* Vt   = K + (size_t)TS * DM;         //               [24, 32)
  u16t* attn = Vt + (size_t)TS * DM;        //               [32, 40)
  u16t* Wb   = attn + (size_t)TS * DM;      // 4 x (D, D)    [40, 72)
  u16t* Wqb = Wb;
  u16t* Wkb = Wb + (size_t)DM * DM;
  u16t* Wvb = Wb + 2 * (size_t)DM * DM;
  u16t* Wob = Wb + 3 * (size_t)DM * DM;

  cast_rms_kernel<<<16384 + TS, 256, 0, stream>>>(Wq, Wk, Wv, Wo, Wb, x, lnw, h);
  // fused QKV: 16x32 tiles = 512 blocks (2/CU, 4 waves/SIMD), gload_lds staging
  gemm_qkv<<<512, 512, 0, stream>>>(h, Wqb, Wkb, Wvb, Q, K, Vt, cosb, sinb);
  attn_kernel<<<NH * (TS / 64), 256, 0, stream>>>(Q, K, Vt, am, attn);
  // out-proj: 128x128 tiles, full K, fused residual+mask epilogue -> out (fp32)
  gemm_out<<<256, 512, 0, stream>>>(attn, Wob, x, am, out);
}

// Round 18
// 256.387 us; speedup vs baseline: 1.2241x; 1.0407x over previous
//
#include <hip/hip_runtime.h>
#include <stdint.h>

#define TS 2048
#define DM 2048
#define NH 16
#define DH 128

typedef unsigned short u16t;
typedef __attribute__((ext_vector_type(8))) short short8;
typedef __attribute__((ext_vector_type(4))) float f32x4;
typedef __attribute__((ext_vector_type(4))) unsigned int u32x4;
typedef __attribute__((ext_vector_type(4))) int i32x4;

__device__ __forceinline__ float bf2f(u16t b) {
  return __uint_as_float(((unsigned int)b) << 16);
}
__device__ __forceinline__ u16t f2bf(float f) {
  unsigned int u = __float_as_uint(f);
  u += 0x7FFFu + ((u >> 16) & 1u);   // round-to-nearest-even
  return (u16t)(u >> 16);
}

// async global->LDS, 16B per lane. LDS dest = wave-uniform base + lane*16.
__device__ __forceinline__ void async_copy16(const u16t* g, u16t* l) {
  __builtin_amdgcn_global_load_lds((const __attribute__((address_space(1))) void*)g,
                                   (__attribute__((address_space(3))) void*)l, 16, 0, 0);
}

// ---------------- fused: fp32->bf16 weight cast (blocks 0..16383) + RMSNorm (rest) ----
// Wq/Wk rows are PERMUTED within each head at cast time so that RoPE partners
// (d, d+64) land at columns (p, p+16): p = (d>>4)*32 + (d&15) [+16 for d>=64].
// In the GEMM C-fragment, col and col+16 are the same lane / adjacent nt register,
// so RoPE becomes a pure in-register epilogue op. Q.K dot is invariant (same perm).
__global__ __launch_bounds__(256) void cast_rms_kernel(const float* __restrict__ W0,
                                                       const float* __restrict__ W1,
                                                       const float* __restrict__ W2,
                                                       const float* __restrict__ W3,
                                                       u16t* __restrict__ outw,
                                                       const float* __restrict__ x,
                                                       const float* __restrict__ lnw,
                                                       u16t* __restrict__ h) {
  if (blockIdx.x < 16384) {
    const int idx = blockIdx.x * 256 + threadIdx.x;   // 4M threads, 4 elems each
    const int mat = idx >> 20;
    const size_t off = (size_t)(idx & 0xFFFFF) * 4;
    const float* W = (mat == 0) ? W0 : (mat == 1) ? W1 : (mat == 2) ? W2 : W3;
    const f32x4 v = *(const f32x4*)(W + off);
    size_t dstoff = off;
    if (mat < 2) {   // permute output-feature rows of Wq, Wk
      const int row = (int)(off >> 11);
      const int col = (int)(off & 2047);
      const int d = row & 127;
      const int e = d & 63;
      const int p = ((e >> 4) * 32 + (e & 15)) + ((d >> 6) << 4);
      dstoff = ((size_t)((row & ~127) | p) << 11) | (size_t)col;
    }
    union { u16t s[4]; uint64_t u; } o;
#pragma unroll
    for (int i = 0; i < 4; ++i) o.s[i] = f2bf(v[i]);
    *(uint64_t*)(outw + (size_t)mat * (DM * DM) + dstoff) = o.u;
    return;
  }
  const int row = blockIdx.x - 16384;
  const int tid = threadIdx.x;
  const float* xr = x + (size_t)row * DM + tid * 8;
  f32x4 v0 = *(const f32x4*)(xr);
  f32x4 v1 = *(const f32x4*)(xr + 4);
  float f[8];
#pragma unroll
  for (int i = 0; i < 4; ++i) { f[i] = v0[i]; f[i + 4] = v1[i]; }
  float ss = 0.f;
#pragma unroll
  for (int i = 0; i < 8; ++i) ss += f[i] * f[i];
#pragma unroll
  for (int off = 1; off < 64; off <<= 1) ss += __shfl_xor(ss, off, 64);
  __shared__ float wsum[4];
  if ((tid & 63) == 0) wsum[tid >> 6] = ss;
  __syncthreads();
  float tot = wsum[0] + wsum[1] + wsum[2] + wsum[3];
  float rs = rsqrtf(tot * (1.0f / DM) + 1e-5f);
  f32x4 w0 = *(const f32x4*)(lnw + tid * 8);
  f32x4 w1 = *(const f32x4*)(lnw + tid * 8 + 4);
  u32x4 o;
#pragma unroll
  for (int i = 0; i < 4; ++i) {
    unsigned int lo = f2bf(f[2 * i]     * ((2 * i     < 4) ? w0[2 * i]     : w1[2 * i - 4]) * rs);
    unsigned int hi = f2bf(f[2 * i + 1] * ((2 * i + 1 < 4) ? w0[2 * i + 1] : w1[2 * i - 3]) * rs);
    o[i] = lo | (hi << 16);
  }
  *(u32x4*)(h + (size_t)row * DM + tid * 8) = o;
}

// ---------------- fused QKV GEMM: 128tok x 64feat x 3 mats, 2 blocks/CU --------------
// (round-17 verified: qkv dropped 79 -> <57 us; total 266.8 — frozen as control)
__global__ __launch_bounds__(512, 4) void gemm_qkv(
    const u16t* __restrict__ A,
    const u16t* __restrict__ B0, const u16t* __restrict__ B1, const u16t* __restrict__ B2,
    u16t* __restrict__ Cq, u16t* __restrict__ Ck, u16t* __restrict__ Cv,
    const float* __restrict__ cosb, const float* __restrict__ sinb) {
  __shared__ u16t Ab[2][128 * 64];      // 32 KB
  __shared__ u16t Bb[3][2][64 * 64];    // 48 KB
  const int tid  = threadIdx.x;
  const int wave = tid >> 6;
  const int lane = tid & 63;
  const int quad = lane >> 4;
  const int c16  = lane & 15;
  const int h7   = c16 & 7;
  const int wm   = wave >> 1;        // 0..3  (32-token slice)
  const int wn   = wave & 1;         // 0..1  (32-feature slice)
  const int bid  = blockIdx.x;
  const int wgid = (bid & 7) * 64 + (bid >> 3);   // XCD swizzle, bijective at 512
  const int m0   = (wgid & 15) * 128;
  const int n0   = (wgid >> 4) * 64;

  const int srow = lane >> 3;               // 0..7
  const int sg   = (lane & 7) ^ srow;       // permuted 16B granule (involution)
  auto stage = [&](int d, int k0) {
    const size_t koff = (size_t)k0 + sg * 8;
#pragma unroll
    for (int c = 0; c < 2; ++c) {           // A: 2 chunks/wave (16 rows)
      const int rb = wave * 16 + c * 8;
      async_copy16(A + (size_t)(m0 + rb + srow) * DM + koff, &Ab[d][rb * 64]);
    }
    const int rbB = wave * 8;               // B: 1 chunk/wave/mat (8 rows)
    async_copy16(B0 + (size_t)(n0 + rbB + srow) * DM + koff, &Bb[0][d][rbB * 64]);
    async_copy16(B1 + (size_t)(n0 + rbB + srow) * DM + koff, &Bb[1][d][rbB * 64]);
    async_copy16(B2 + (size_t)(n0 + rbB + srow) * DM + koff, &Bb[2][d][rbB * 64]);
  };

  const f32x4 fzero = {0.f, 0.f, 0.f, 0.f};
  f32x4 acc[3][2][2];   // [mat][mt][nt] -> 48 VGPR
#pragma unroll
  for (int m = 0; m < 3; ++m)
#pragma unroll
    for (int i = 0; i < 2; ++i)
#pragma unroll
      for (int j = 0; j < 2; ++j) acc[m][i][j] = fzero;

  stage(0, 0);
  asm volatile("s_waitcnt vmcnt(0)" ::: "memory");
  __builtin_amdgcn_s_barrier();

  for (int kt = 0; kt < DM / 64; ++kt) {
    const int cur = kt & 1;
    if (kt + 1 < DM / 64) stage(cur ^ 1, (kt + 1) * 64);   // prefetch under compute
    const u16t* Abuf = Ab[cur];
    __builtin_amdgcn_s_setprio(1);
#pragma unroll
    for (int ks = 0; ks < 2; ++ks) {       // two K=32 halves
      const int gsw = ((ks * 4 + quad) ^ h7) * 8;
      short8 af[2], bfr[3][2];
#pragma unroll
      for (int i = 0; i < 2; ++i)
        af[i] = *(const short8*)(Abuf + (wm * 32 + i * 16 + c16) * 64 + gsw);
#pragma unroll
      for (int m = 0; m < 3; ++m)
#pragma unroll
        for (int nt = 0; nt < 2; ++nt)
          bfr[m][nt] = *(const short8*)(&Bb[m][cur][0] + (wn * 32 + nt * 16 + c16) * 64 + gsw);
#pragma unroll
      for (int m = 0; m < 3; ++m)
#pragma unroll
        for (int i = 0; i < 2; ++i)
#pragma unroll
          for (int nt = 0; nt < 2; ++nt)
            acc[m][i][nt] =
                __builtin_amdgcn_mfma_f32_16x16x32_bf16(af[i], bfr[m][nt], acc[m][i][nt], 0, 0, 0);
    }
    __builtin_amdgcn_s_setprio(0);
    asm volatile("s_waitcnt vmcnt(0)" ::: "memory");
    __builtin_amdgcn_s_barrier();
  }

  // Q/K with fused RoPE: each wave's cols are (p, p+16) pairs, p = col & 127
  // (bit4 of col is 0: n0 % 64 == 0, wn*32 keeps bit4 clear, c16 < 16).
#pragma unroll
  for (int mat = 0; mat < 2; ++mat) {
    u16t* C = mat ? Ck : Cq;
#pragma unroll
    for (int mt = 0; mt < 2; ++mt) {
#pragma unroll
      for (int r = 0; r < 4; ++r) {
        const int row = m0 + wm * 32 + mt * 16 + quad * 4 + r;   // = token t
        const size_t base = (size_t)row * DM;
        const int col = n0 + wn * 32 + c16;
        const int p = col & 127;
        const int dorig = ((p >> 5) << 4) + c16;
        const float cv = cosb[row * DH + dorig];
        const float sv = sinb[row * DH + dorig];
        const float x1 = acc[mat][mt][0][r];
        const float x2 = acc[mat][mt][1][r];
        C[base + col]      = f2bf(x1 * cv - x2 * sv);
        C[base + col + 16] = f2bf(x2 * cv + x1 * sv);
      }
    }
  }
  // V: transposed store
#pragma unroll
  for (int mt = 0; mt < 2; ++mt) {
#pragma unroll
    for (int r = 0; r < 4; ++r) {
      const int row = m0 + wm * 32 + mt * 16 + quad * 4 + r;
#pragma unroll
      for (int nt = 0; nt < 2; ++nt) {
        const int col = n0 + wn * 32 + nt * 16 + c16;
        Cv[(size_t)col * TS + row] = f2bf(acc[2][mt][nt][r]);
      }
    }
  }
}

// ---------------- out-proj GEMM: 128tok x 64feat, FULL K, 2+ blocks/CU ----------------
// Round-17 post-mortem: budget accounting exposed the r12 gemm_out (128^2 full-K,
// 1 block/CU) as a ~50 us hog — same latency-bound per-K-tile loop QKV just escaped.
// Fix: clone the VERIFIED r17 QKV structure (128x64 tiles, 512 blocks, 8 waves 4m x 2n,
// LDS A 32KB + B 16KB = 48 KB, launch_bounds(512,4)) with one matrix; epilogue fuses
// out = x + mask_row * acc (fp32 direct).
__global__ __launch_bounds__(512, 4) void gemm_out(
    const u16t* __restrict__ A, const u16t* __restrict__ B0,
    const float* __restrict__ xres, const int* __restrict__ am,
    float* __restrict__ out) {
  __shared__ u16t Ab[2][128 * 64];   // 32 KB
  __shared__ u16t Bb[2][64 * 64];    // 16 KB
  const int tid  = threadIdx.x;
  const int wave = tid >> 6;
  const int lane = tid & 63;
  const int quad = lane >> 4;
  const int c16  = lane & 15;
  const int h7   = c16 & 7;
  const int wm   = wave >> 1;        // 0..3  (32-row slice)
  const int wn   = wave & 1;         // 0..1  (32-col slice)
  const int bid  = blockIdx.x;
  const int wgid = (bid & 7) * 64 + (bid >> 3);   // XCD swizzle, bijective at 512
  const int m0   = (wgid & 15) * 128;
  const int n0   = (wgid >> 4) * 64;

  const int srow = lane >> 3;               // 0..7
  const int sg   = (lane & 7) ^ srow;       // permuted 16B granule (involution)
  auto stage = [&](int d, int k0) {
    const size_t koff = (size_t)k0 + sg * 8;
#pragma unroll
    for (int c = 0; c < 2; ++c) {           // A: 2 chunks/wave (16 rows)
      const int rb = wave * 16 + c * 8;
      async_copy16(A + (size_t)(m0 + rb + srow) * DM + koff, &Ab[d][rb * 64]);
    }
    const int rbB = wave * 8;               // B: 1 chunk/wave (8 rows)
    async_copy16(B0 + (size_t)(n0 + rbB + srow) * DM + koff, &Bb[d][rbB * 64]);
  };

  const f32x4 fzero = {0.f, 0.f, 0.f, 0.f};
  f32x4 acc[2][2];   // [mt][nt] -> 16 VGPR
#pragma unroll
  for (int i = 0; i < 2; ++i)
#pragma unroll
    for (int j = 0; j < 2; ++j) acc[i][j] = fzero;

  stage(0, 0);
  asm volatile("s_waitcnt vmcnt(0)" ::: "memory");
  __builtin_amdgcn_s_barrier();

  for (int kt = 0; kt < DM / 64; ++kt) {
    const int cur = kt & 1;
    if (kt + 1 < DM / 64) stage(cur ^ 1, (kt + 1) * 64);   // prefetch under compute
    const u16t* Abuf = Ab[cur];
    const u16t* Bbuf = Bb[cur];
    __builtin_amdgcn_s_setprio(1);
#pragma unroll
    for (int ks = 0; ks < 2; ++ks) {       // two K=32 halves
      const int gsw = ((ks * 4 + quad) ^ h7) * 8;
      short8 af[2], bfr[2];
#pragma unroll
      for (int i = 0; i < 2; ++i)
        af[i] = *(const short8*)(Abuf + (wm * 32 + i * 16 + c16) * 64 + gsw);
#pragma unroll
      for (int nt = 0; nt < 2; ++nt)
        bfr[nt] = *(const short8*)(Bbuf + (wn * 32 + nt * 16 + c16) * 64 + gsw);
#pragma unroll
      for (int i = 0; i < 2; ++i)
#pragma unroll
        for (int nt = 0; nt < 2; ++nt)
          acc[i][nt] =
              __builtin_amdgcn_mfma_f32_16x16x32_bf16(af[i], bfr[nt], acc[i][nt], 0, 0, 0);
    }
    __builtin_amdgcn_s_setprio(0);
    asm volatile("s_waitcnt vmcnt(0)" ::: "memory");
    __builtin_amdgcn_s_barrier();
  }

  // fused residual + row-mask epilogue, fp32 store direct to output
#pragma unroll
  for (int mt = 0; mt < 2; ++mt) {
#pragma unroll
    for (int r = 0; r < 4; ++r) {
      const int row = m0 + wm * 32 + mt * 16 + quad * 4 + r;
      const float mk = (am[row] != 0) ? 1.f : 0.f;
      const size_t base = (size_t)row * DM;
#pragma unroll
      for (int nt = 0; nt < 2; ++nt) {
        const int col = n0 + wn * 32 + nt * 16 + c16;
        out[base + col] = xres[base + col] + mk * acc[mt][nt][r];
      }
    }
  }
}

// ---------------- Flash attention (causal), SWAPPED QK^T, in-register softmax ----------
// (round-13/17 verified: 57 us — frozen as control)
__global__ __launch_bounds__(256) void attn_kernel(const u16t* __restrict__ Q,
                                                   const u16t* __restrict__ K,
                                                   const u16t* __restrict__ Vt,
                                                   const int* __restrict__ am,
                                                   u16t* __restrict__ O) {
  __shared__ u16t Klds[128 * 128];   // [key][d], swizzled granules, 32 KB
  __shared__ u16t Vlds[128 * 128];   // [d][key], swizzled granules, 32 KB
  __shared__ u16t Plds[4][2048];     // per-wave P (packed u32) / O-transpose, 16 KB
  const int wave = threadIdx.x >> 6;
  const int lane = threadIdx.x & 63;
  const int x    = blockIdx.x;
  const int half = x >> 8;                  // 0: qt 31..16, 1: qt 0..15
  const int idx  = x & 255;
  const int head = idx & (NH - 1);
  const int grp  = idx >> 4;                // 0..15
  const int qt   = half ? grp : (TS / 64 - 1 - grp);
  const int q0   = qt * 64 + wave * 16;
  const int quad = lane >> 4;
  const int c16  = lane & 15;
  const u16t* Qh  = Q + head * DH;
  const u16t* Kh  = K + head * DH;
  const u16t* Vth = Vt + (size_t)head * DH * TS;
  u16t* Pw = Plds[wave];
  uint32_t* Pw32 = (uint32_t*)Pw;
  const int pswz = (c16 & 7) << 2;          // u32-level XOR (bits 2-4), b128-safe

  const int row_s = (lane >> 4);    // 0..3 row within chunk
  const int g_s   = (lane & 15);    // granule slot

  short8 qf[4];
#pragma unroll
  for (int dc = 0; dc < 4; ++dc)
    qf[dc] = *(const short8*)(Qh + (size_t)(q0 + c16) * DM + dc * 32 + quad * 8);

  const f32x4 fzero = {0.f, 0.f, 0.f, 0.f};
  float m_run = -1e30f, l_run = 0.f;
  f32x4 o_acc[8];                   // out^T[d = mt*16+quad*4+r][q = c16]
#pragma unroll
  for (int mt = 0; mt < 8; ++mt) o_acc[mt] = fzero;

  const float scale = 0.08838834764831845f;  // 1/sqrt(128)
  const int ntiles = (qt * 64 + 191) >> 7;   // 128-wide tiles covering keys 0..q0+63
  const int qrow = q0 + c16;

  for (int kt = 0; kt < ntiles; ++kt) {
    const int k0 = kt * 128;
    __syncthreads();
#pragma unroll
    for (int c = 0; c < 8; ++c) {
      const int ch = wave * 8 + c;
      const int r  = 4 * ch + row_s;           // 0..127
      const int g  = g_s ^ (r & 15);
      async_copy16(Kh + (size_t)(k0 + r) * DM + g * 8, Klds + ch * 512);
      async_copy16(Vth + (size_t)r * TS + k0 + g * 8, Vlds + ch * 512);
    }
    __syncthreads();

    // S^T = K . Q^T : lane holds S^T[key = k0+ns*16+quad*4+r][q = qrow]
    f32x4 s[8];
#pragma unroll
    for (int ns = 0; ns < 8; ++ns) {
      f32x4 sa = fzero;
      const int rr = ns * 16 + c16;
#pragma unroll
      for (int dc = 0; dc < 4; ++dc) {
        short8 kf = *(const short8*)(Klds + rr * 128 + (((dc * 4 + quad) ^ c16) * 8));
        sa = __builtin_amdgcn_mfma_f32_16x16x32_bf16(kf, qf[dc], sa, 0, 0, 0);
      }
      s[ns] = sa;
    }

    // mask + in-lane max over this q-row's 32 keys
    float pv[8][4];
    float tmax = -1e30f;
#pragma unroll
    for (int ns = 0; ns < 8; ++ns) {
      const i32x4 a4 = *(const i32x4*)(am + k0 + ns * 16 + quad * 4);
#pragma unroll
      for (int r = 0; r < 4; ++r) {
        const int key = k0 + ns * 16 + quad * 4 + r;
        float v = s[ns][r] * scale;
        if (key > qrow || a4[r] == 0) v = -1e30f;
        pv[ns][r] = v;
        tmax = fmaxf(tmax, v);
      }
    }
    // full-row reduce across the 4 quads holding this q-row
    tmax = fmaxf(tmax, __shfl_xor(tmax, 16, 64));
    tmax = fmaxf(tmax, __shfl_xor(tmax, 32, 64));
    const float mn = fmaxf(m_run, tmax);
    const float alpha = __expf(m_run - mn);
    m_run = mn;
    float rs = 0.f;
#pragma unroll
    for (int ns = 0; ns < 8; ++ns)
#pragma unroll
      for (int r = 0; r < 4; ++r) {
        const float e = __expf(pv[ns][r] - mn);
        pv[ns][r] = e;
        rs += e;
      }
    rs += __shfl_xor(rs, 16, 64);
    rs += __shfl_xor(rs, 32, 64);
    l_run = l_run * alpha + rs;

    // pack P to bf16 pairs; store as [q=c16 row][key-pair], XOR-swizzled u32 layout.
    // logical u32 L = ns*8 + quad*2 + i covers keys ns*16+quad*4+2i, +2i+1.
#pragma unroll
    for (int ns = 0; ns < 8; ++ns)
#pragma unroll
      for (int i = 0; i < 2; ++i) {
        uint32_t pk;
        asm("v_cvt_pk_bf16_f32 %0, %1, %2"
            : "=v"(pk) : "v"(pv[ns][2 * i]), "v"(pv[ns][2 * i + 1]));
        Pw32[c16 * 64 + ((ns * 8 + quad * 2 + i) ^ pswz)] = pk;
      }
    asm volatile("s_waitcnt lgkmcnt(0)" ::: "memory");
    // B-fragments: pa[kb] = P[q=c16][keys kb*32 + quad*8 + 0..7]
    short8 pa[4];
#pragma unroll
    for (int kb = 0; kb < 4; ++kb)
      pa[kb] = *(const short8*)(Pw32 + c16 * 64 + ((kb * 16 + quad * 4) ^ pswz));

    // rescale + PV: o_acc[mt] = mfma(A = Vt[d-rows], B = pa)
#pragma unroll
    for (int mt = 0; mt < 8; ++mt)
#pragma unroll
      for (int r = 0; r < 4; ++r) o_acc[mt][r] *= alpha;
#pragma unroll
    for (int mt = 0; mt < 8; ++mt) {
      const int rrv = mt * 16 + c16;           // d-row
#pragma unroll
      for (int kb = 0; kb < 4; ++kb) {
        short8 vf = *(const short8*)(Vlds + rrv * 128 + (((kb * 4 + quad) ^ c16) * 8));
        o_acc[mt] = __builtin_amdgcn_mfma_f32_16x16x32_bf16(vf, pa[kb], o_acc[mt], 0, 0, 0);
      }
    }
  }

  // epilogue: normalize, transpose via per-wave LDS, coalesced 16B stores
  const float inv = 1.0f / fmaxf(l_run, 1e-20f);
#pragma unroll
  for (int mt = 0; mt < 8; ++mt)
#pragma unroll
    for (int r = 0; r < 4; ++r) {
      const int d = mt * 16 + quad * 4 + r;
      Pw[c16 * 128 + d] = f2bf(o_acc[mt][r] * inv);
    }
  asm volatile("s_waitcnt lgkmcnt(0)" ::: "memory");
#pragma unroll
  for (int p = 0; p < 4; ++p) {
    const int row = p * 4 + quad;              // q-local 0..15
    short8 v = *(const short8*)(Pw + row * 128 + c16 * 8);
    *(short8*)(O + (size_t)(q0 + row) * DM + head * DH + c16 * 8) = v;
  }
}

extern "C" void kernel_launch(void* const* d_in, const int* in_sizes, int n_in,
                              void* d_out, int out_size, void* d_ws, size_t ws_size,
                              hipStream_t stream) {
  const float* x    = (const float*)d_in[0];
  const float* cosb = (const float*)d_in[1];
  const float* sinb = (const float*)d_in[2];
  const int*   am   = (const int*)d_in[3];
  const float* lnw  = (const float*)d_in[4];
  const float* Wq   = (const float*)d_in[5];
  const float* Wk   = (const float*)d_in[6];
  const float* Wv   = (const float*)d_in[7];
  const float* Wo   = (const float*)d_in[8];
  float* out = (float*)d_out;

  u16t* h    = (u16t*)d_ws;                 // (T, D) bf16   [0, 8 MB)
  u16t* Q    = h + (size_t)TS * DM;         //               [8, 16)
  u16t* K    = Q + (size_t)TS * DM;         //               [16, 24)
  u16t* Vt   = K + (size_t)TS * DM;         //               [24, 32)
  u16t* attn = Vt + (size_t)TS * DM;        //               [32, 40)
  u16t* Wb   = attn + (size_t)TS * DM;      // 4 x (D, D)    [40, 72)
  u16t* Wqb = Wb;
  u16t* Wkb = Wb + (size_t)DM * DM;
  u16t* Wvb = Wb + 2 * (size_t)DM * DM;
  u16t* Wob = Wb + 3 * (size_t)DM * DM;

  cast_rms_kernel<<<16384 + TS, 256, 0, stream>>>(Wq, Wk, Wv, Wo, Wb, x, lnw, h);
  // fused QKV: 16x32 tiles = 512 blocks (2/CU, 4 waves/SIMD), gload_lds staging
  gemm_qkv<<<512, 512, 0, stream>>>(h, Wqb, Wkb, Wvb, Q, K, Vt, cosb, sinb);
  attn_kernel<<<NH * (TS / 64), 256, 0, stream>>>(Q, K, Vt, am, attn);
  // out-proj: 16x32 tiles = 512 blocks (2/CU), full K, fused residual epilogue
  gemm_out<<<512, 512, 0, stream>>>(attn, Wob, x, am, out);
}